// Round 1
// baseline (7692.747 us; speedup 1.0000x reference)
//
#include <hip/hip_runtime.h>
#include <stdint.h>
#include <math.h>

#define NANCH 261888
#define NBATCH 16
#define PRE_NMS 12000
#define POST_NMS 2000
#define NMS_J 12   // 1024 threads * 12 slots = 12288 >= 12000

// ---------- key construction: (ordered score bits << 32) | ~index ----------
// Unique per element; larger key == (higher score, or equal score + lower index).
__device__ __forceinline__ uint64_t make_key(float s, int i) {
    uint32_t u = __float_as_uint(s);
    u ^= (u >> 31) ? 0xFFFFFFFFu : 0x80000000u;   // total order for floats
    return ((uint64_t)u << 32) | (uint32_t)(~(uint32_t)i);
}

// ---------- init: zero hist/cnt, set prefix/kth (ws is poisoned 0xAA) ----------
__global__ void k_init(uint32_t* hist, uint64_t* prefix, uint32_t* kth, uint32_t* cnt) {
    int tid = threadIdx.x;
    for (int i = tid; i < NBATCH * 256; i += blockDim.x) hist[i] = 0;
    if (tid < NBATCH) { prefix[tid] = 0; kth[tid] = PRE_NMS; cnt[tid] = 0; }
}

// ---------- radix-select histogram pass over 8-bit digits, MSB first ----------
__global__ void k_hist(const float* __restrict__ scores, uint32_t* __restrict__ hist,
                       const uint64_t* __restrict__ prefix, int pass) {
    __shared__ uint32_t lh[256];
    int tid = threadIdx.x;
    int b = blockIdx.y;
    lh[tid] = 0;
    __syncthreads();
    uint64_t pfx = prefix[b];
    int sp = 64 - 8 * pass;   // bits already fixed
    int sd = 56 - 8 * pass;   // digit position
    const float* sc = scores + (size_t)b * NANCH;
    for (int i = blockIdx.x * 256 + tid; i < NANCH; i += gridDim.x * 256) {
        uint64_t key = make_key(sc[i], i);
        bool cand = (pass == 0) || ((key >> sp) == (pfx >> sp));
        if (cand) atomicAdd(&lh[(uint32_t)(key >> sd) & 0xFFu], 1u);
    }
    __syncthreads();
    uint32_t c = lh[tid];
    if (c) atomicAdd(&hist[b * 256 + tid], c);
}

// ---------- pick digit containing the kth largest; reset hist for next pass ----
__global__ void k_pick(uint32_t* hist, uint64_t* prefix, uint32_t* kth, int pass) {
    __shared__ uint32_t h[256];
    int tid = threadIdx.x;
    int b = blockIdx.x;
    h[tid] = hist[b * 256 + tid];
    hist[b * 256 + tid] = 0;
    __syncthreads();
    if (tid == 0) {
        uint32_t k = kth[b];
        uint32_t cum = 0;
        int d = 255;
        for (; d > 0; --d) {
            uint32_t c = h[d];
            if (cum + c >= k) break;
            cum += c;
        }
        kth[b] = k - cum;
        prefix[b] |= ((uint64_t)(uint32_t)d) << (56 - 8 * pass);
    }
}

// ---------- compact: every key >= threshold (exactly PRE_NMS, keys unique) ----
__global__ void k_compact(const float* __restrict__ scores, const uint64_t* __restrict__ prefix,
                          uint32_t* __restrict__ cnt, uint64_t* __restrict__ selk) {
    int tid = threadIdx.x;
    int b = blockIdx.y;
    uint64_t T = prefix[b];
    const float* sc = scores + (size_t)b * NANCH;
    for (int i = blockIdx.x * 256 + tid; i < NANCH; i += gridDim.x * 256) {
        uint64_t key = make_key(sc[i], i);
        if (key >= T) {
            uint32_t p = atomicAdd(&cnt[b], 1u);
            if (p < PRE_NMS) selk[(size_t)b * PRE_NMS + p] = key;
        }
    }
}

// ---------- rank sort: rank = #{keys > mine}; scatter anchor idx to rank -----
#define RNK_RPT 4
__global__ void k_rank(const uint64_t* __restrict__ selk, uint32_t* __restrict__ aidx) {
    __shared__ uint64_t ch[2048];
    int tid = threadIdx.x;
    int b = blockIdx.y;
    const uint64_t* keys = selk + (size_t)b * PRE_NMS;
    uint64_t mine[RNK_RPT];
    int rank[RNK_RPT];
    int base = blockIdx.x * (256 * RNK_RPT) + tid;
    #pragma unroll
    for (int r = 0; r < RNK_RPT; ++r) {
        int e = base + r * 256;
        mine[r] = (e < PRE_NMS) ? keys[e] : 0;
        rank[r] = 0;
    }
    for (int c0 = 0; c0 < PRE_NMS; c0 += 2048) {
        for (int j = tid; j < 2048; j += 256) {
            int g = c0 + j;
            ch[j] = (g < PRE_NMS) ? keys[g] : 0;   // pad 0 < any real key
        }
        __syncthreads();
        #pragma unroll 8
        for (int j = 0; j < 2048; ++j) {
            uint64_t kj = ch[j];
            #pragma unroll
            for (int r = 0; r < RNK_RPT; ++r) rank[r] += (kj > mine[r]) ? 1 : 0;
        }
        __syncthreads();
    }
    #pragma unroll
    for (int r = 0; r < RNK_RPT; ++r) {
        int e = base + r * 256;
        if (e < PRE_NMS) aidx[(size_t)b * PRE_NMS + rank[r]] = ~(uint32_t)(mine[r] & 0xFFFFFFFFull);
    }
}

// ---------- gather + bbox decode + clip (no FMA contraction; exp via double) --
__global__ void k_gather(const float4* __restrict__ anchors, const float4* __restrict__ deltas,
                         const float* __restrict__ im_info, const uint32_t* __restrict__ aidx,
                         float4* __restrict__ props, float* __restrict__ areas) {
    int b = blockIdx.y;
    int i = blockIdx.x * 256 + threadIdx.x;
    if (i >= PRE_NMS) return;
    uint32_t a = aidx[(size_t)b * PRE_NMS + i];
    float4 an = anchors[a];
    float4 dl = deltas[(size_t)b * NANCH + a];
    float w  = __fadd_rn(__fsub_rn(an.z, an.x), 1.0f);
    float h  = __fadd_rn(__fsub_rn(an.w, an.y), 1.0f);
    float cx = __fadd_rn(an.x, __fmul_rn(0.5f, w));
    float cy = __fadd_rn(an.y, __fmul_rn(0.5f, h));
    float pcx = __fadd_rn(__fmul_rn(dl.x, w), cx);
    float pcy = __fadd_rn(__fmul_rn(dl.y, h), cy);
    float ew = (float)exp((double)dl.z);
    float eh = (float)exp((double)dl.w);
    float pw = __fmul_rn(ew, w);
    float ph = __fmul_rn(eh, h);
    float x1 = __fsub_rn(pcx, __fmul_rn(0.5f, pw));
    float y1 = __fsub_rn(pcy, __fmul_rn(0.5f, ph));
    float x2 = __fadd_rn(pcx, __fmul_rn(0.5f, pw));
    float y2 = __fadd_rn(pcy, __fmul_rn(0.5f, ph));
    float xmax = __fsub_rn(im_info[b * 3 + 1], 1.0f);
    float ymax = __fsub_rn(im_info[b * 3 + 0], 1.0f);
    x1 = fminf(fmaxf(x1, 0.0f), xmax);
    y1 = fminf(fmaxf(y1, 0.0f), ymax);
    x2 = fminf(fmaxf(x2, 0.0f), xmax);
    y2 = fminf(fmaxf(y2, 0.0f), ymax);
    props[(size_t)b * PRE_NMS + i] = make_float4(x1, y1, x2, y2);
    areas[(size_t)b * PRE_NMS + i] =
        __fmul_rn(__fadd_rn(__fsub_rn(x2, x1), 1.0f), __fadd_rn(__fsub_rn(y2, y1), 1.0f));
}

// ---------- greedy NMS: 1 workgroup/batch, register boxes, LDS bitmask -------
__global__ __launch_bounds__(1024) void k_nms(const float4* __restrict__ props,
                                              const float* __restrict__ areas,
                                              float* __restrict__ out) {
    int b = blockIdx.x;
    int tid = threadIdx.x;
    int wv = tid >> 6, ln = tid & 63;
    const float4* P = props + (size_t)b * PRE_NMS;
    const float* A = areas + (size_t)b * PRE_NMS;
    float bx1[NMS_J], by1[NMS_J], bx2[NMS_J], by2[NMS_J], bar[NMS_J];
    uint32_t vm = 0;
    #pragma unroll
    for (int j = 0; j < NMS_J; ++j) {
        int slot = tid + 1024 * j;
        if (slot < PRE_NMS) {
            float4 p = P[slot];
            bx1[j] = p.x; by1[j] = p.y; bx2[j] = p.z; by2[j] = p.w;
            bar[j] = A[slot];
            vm |= (1u << j);
        } else { bx1[j] = 0; by1[j] = 0; bx2[j] = 0; by2[j] = 0; bar[j] = 1.0f; }
    }
    __shared__ uint32_t mask[384];   // 12288 bits
    __shared__ float sbox[5];
    __shared__ int ssel;
    #pragma unroll
    for (int j = 0; j < NMS_J; ++j) {
        unsigned long long bal = __ballot((vm >> j) & 1);
        if (ln == 0) {
            int w0 = (wv * 64 + 1024 * j) >> 5;
            mask[w0] = (uint32_t)bal;
            mask[w0 + 1] = (uint32_t)(bal >> 32);
        }
    }
    int curw = 0;   // monotone find-first pointer (thread 0 only)
    float* outb = out + (size_t)b * POST_NMS * 5;
    __syncthreads();
    for (int it = 0; it < POST_NMS; ++it) {
        if (tid == 0) {
            while (curw < 384 && mask[curw] == 0u) curw++;
            int sel = -1;
            if (curw < 384) {
                sel = (curw << 5) + __ffs(mask[curw]) - 1;
                float4 pb = P[sel];
                sbox[0] = pb.x; sbox[1] = pb.y; sbox[2] = pb.z; sbox[3] = pb.w;
                sbox[4] = A[sel];
            }
            ssel = sel;
        }
        __syncthreads();
        int sel = ssel;
        if (sel < 0) {   // exhausted: remaining rows are [b,0,0,0,0]
            for (int r = it + tid; r < POST_NMS; r += 1024) {
                outb[(size_t)r * 5 + 0] = (float)b;
                outb[(size_t)r * 5 + 1] = 0.0f;
                outb[(size_t)r * 5 + 2] = 0.0f;
                outb[(size_t)r * 5 + 3] = 0.0f;
                outb[(size_t)r * 5 + 4] = 0.0f;
            }
            break;
        }
        float sx1 = sbox[0], sy1 = sbox[1], sx2 = sbox[2], sy2 = sbox[3], sa = sbox[4];
        if (tid < 5) outb[(size_t)it * 5 + tid] = (tid == 0) ? (float)b : sbox[tid - 1];
        #pragma unroll
        for (int j = 0; j < NMS_J; ++j) {
            bool v = (vm >> j) & 1;
            unsigned long long bal = __ballot(v);
            if (bal == 0ull) continue;   // whole wave dead for this group; word already 0
            if (v) {
                float xx1 = fmaxf(sx1, bx1[j]);
                float yy1 = fmaxf(sy1, by1[j]);
                float xx2 = fminf(sx2, bx2[j]);
                float yy2 = fminf(sy2, by2[j]);
                float ww = fmaxf(__fadd_rn(__fsub_rn(xx2, xx1), 1.0f), 0.0f);
                float hh = fmaxf(__fadd_rn(__fsub_rn(yy2, yy1), 1.0f), 0.0f);
                float inter = __fmul_rn(ww, hh);
                float denom = __fsub_rn(__fadd_rn(sa, bar[j]), inter);
                float iou = __fdiv_rn(inter, denom);
                if (!(iou <= 0.7f)) v = false;   // matches valid & (iou <= thresh)
            }
            unsigned long long nb = __ballot(v);
            if (!v) vm &= ~(1u << j);
            if (nb != bal && ln == 0) {
                int w0 = (wv * 64 + 1024 * j) >> 5;
                mask[w0] = (uint32_t)nb;
                mask[w0 + 1] = (uint32_t)(nb >> 32);
            }
        }
        __syncthreads();
    }
}

extern "C" void kernel_launch(void* const* d_in, const int* in_sizes, int n_in,
                              void* d_out, int out_size, void* d_ws, size_t ws_size,
                              hipStream_t stream) {
    const float* scores  = (const float*)d_in[0];
    const float* deltas  = (const float*)d_in[1];
    const float* im_info = (const float*)d_in[2];
    const float* anchors = (const float*)d_in[3];
    float* out = (float*)d_out;

    // workspace layout (all 16B-aligned where needed), total ~6.2 MB
    uint8_t* w = (uint8_t*)d_ws;
    uint32_t* hist   = (uint32_t*)(w);                       // 16384 B
    uint64_t* prefix = (uint64_t*)(w + 16384);               // 128 B
    uint32_t* kth    = (uint32_t*)(w + 16512);               // 64 B
    uint32_t* cnt    = (uint32_t*)(w + 16576);               // 64 B
    uint64_t* selk   = (uint64_t*)(w + 16640);               // 1,536,000 B
    uint32_t* aidx   = (uint32_t*)(w + 16640 + 1536000);     // 768,000 B
    float*    props  = (float*)(w + 2320640);                // 3,072,000 B
    float*    areas  = (float*)(w + 5392640);                // 768,000 B

    hipLaunchKernelGGL(k_init, dim3(1), dim3(1024), 0, stream, hist, prefix, kth, cnt);
    for (int p = 0; p < 8; ++p) {
        hipLaunchKernelGGL(k_hist, dim3(128, NBATCH), dim3(256), 0, stream, scores, hist, prefix, p);
        hipLaunchKernelGGL(k_pick, dim3(NBATCH), dim3(256), 0, stream, hist, prefix, kth, p);
    }
    hipLaunchKernelGGL(k_compact, dim3(128, NBATCH), dim3(256), 0, stream, scores, prefix, cnt, selk);
    hipLaunchKernelGGL(k_rank, dim3(12, NBATCH), dim3(256), 0, stream, selk, aidx);
    hipLaunchKernelGGL(k_gather, dim3(47, NBATCH), dim3(256), 0, stream,
                       (const float4*)anchors, (const float4*)deltas, im_info, aidx,
                       (float4*)props, areas);
    hipLaunchKernelGGL(k_nms, dim3(NBATCH), dim3(1024), 0, stream,
                       (const float4*)props, areas, out);
}

// Round 2
// 4694.214 us; speedup vs baseline: 1.6388x; 1.6388x over previous
//
#include <hip/hip_runtime.h>
#include <stdint.h>
#include <math.h>

#define NANCH 261888
#define NBATCH 16
#define PRE_NMS 12000
#define POST_NMS 2000
#define NSLOT 12          // 1024 threads * 12 = 12288 slots >= 12000
#define MASKW 384         // 12288 bits / 32
#define BCACHE 3000       // boxes cached in LDS for selection loads

// ---------- key construction: (ordered score bits << 32) | ~index ----------
__device__ __forceinline__ uint64_t make_key(float s, int i) {
    uint32_t u = __float_as_uint(s);
    u ^= (u >> 31) ? 0xFFFFFFFFu : 0x80000000u;   // total order for floats
    return ((uint64_t)u << 32) | (uint32_t)(~(uint32_t)i);
}

// ---------- init ----------
__global__ void k_init(uint32_t* hist, uint64_t* prefix, uint32_t* kth, uint32_t* cnt) {
    int tid = threadIdx.x;
    for (int i = tid; i < NBATCH * 256; i += blockDim.x) hist[i] = 0;
    if (tid < NBATCH) { prefix[tid] = 0; kth[tid] = PRE_NMS; cnt[tid] = 0; }
}

// ---------- radix-select histogram pass over 8-bit digits, MSB first ----------
__global__ void k_hist(const float* __restrict__ scores, uint32_t* __restrict__ hist,
                       const uint64_t* __restrict__ prefix, int pass) {
    __shared__ uint32_t lh[256];
    int tid = threadIdx.x;
    int b = blockIdx.y;
    lh[tid] = 0;
    __syncthreads();
    uint64_t pfx = prefix[b];
    int sp = 64 - 8 * pass;
    int sd = 56 - 8 * pass;
    const float* sc = scores + (size_t)b * NANCH;
    for (int i = blockIdx.x * 256 + tid; i < NANCH; i += gridDim.x * 256) {
        uint64_t key = make_key(sc[i], i);
        bool cand = (pass == 0) || ((key >> sp) == (pfx >> sp));
        if (cand) atomicAdd(&lh[(uint32_t)(key >> sd) & 0xFFu], 1u);
    }
    __syncthreads();
    uint32_t c = lh[tid];
    if (c) atomicAdd(&hist[b * 256 + tid], c);
}

// ---------- pick digit containing kth largest; reset hist ----------
__global__ void k_pick(uint32_t* hist, uint64_t* prefix, uint32_t* kth, int pass) {
    __shared__ uint32_t h[256];
    int tid = threadIdx.x;
    int b = blockIdx.x;
    h[tid] = hist[b * 256 + tid];
    hist[b * 256 + tid] = 0;
    __syncthreads();
    if (tid == 0) {
        uint32_t k = kth[b];
        uint32_t cum = 0;
        int d = 255;
        for (; d > 0; --d) {
            uint32_t c = h[d];
            if (cum + c >= k) break;
            cum += c;
        }
        kth[b] = k - cum;
        prefix[b] |= ((uint64_t)(uint32_t)d) << (56 - 8 * pass);
    }
}

// ---------- compact: wave-aggregated LDS staging, 1 global atomic per block ----
__global__ __launch_bounds__(256) void k_compact(const float* __restrict__ scores,
                                                 const uint64_t* __restrict__ prefix,
                                                 uint32_t* __restrict__ cnt,
                                                 uint64_t* __restrict__ selk) {
    __shared__ uint32_t lcnt, lbase;
    __shared__ uint64_t lbuf[2048];
    int tid = threadIdx.x;
    int b = blockIdx.y;
    int ln = tid & 63;
    if (tid == 0) lcnt = 0;
    __syncthreads();
    uint64_t T = prefix[b];
    const float* sc = scores + (size_t)b * NANCH;
    int base0 = blockIdx.x * 2048;
    for (int r = 0; r < 8; ++r) {
        int i = base0 + r * 256 + tid;
        bool pred = false;
        uint64_t key = 0;
        if (i < NANCH) { key = make_key(sc[i], i); pred = key >= T; }
        unsigned long long bal = __ballot(pred);
        uint32_t wb = 0;
        if (ln == 0 && bal) wb = atomicAdd(&lcnt, (uint32_t)__popcll(bal));
        wb = __shfl(wb, 0);
        if (pred) lbuf[wb + (uint32_t)__popcll(bal & ((1ull << ln) - 1ull))] = key;
    }
    __syncthreads();
    if (tid == 0) lbase = atomicAdd(&cnt[b], lcnt);
    __syncthreads();
    uint32_t n = lcnt, bs = lbase;
    for (uint32_t i = tid; i < n; i += 256) {
        uint32_t p = bs + i;
        if (p < PRE_NMS) selk[(size_t)b * PRE_NMS + p] = lbuf[i];
    }
}

// ---------- rank sort: rank = #{keys > mine}; scatter anchor idx to rank -----
#define RNK_RPT 4
__global__ void k_rank(const uint64_t* __restrict__ selk, uint32_t* __restrict__ aidx) {
    __shared__ uint64_t ch[2048];
    int tid = threadIdx.x;
    int b = blockIdx.y;
    const uint64_t* keys = selk + (size_t)b * PRE_NMS;
    uint64_t mine[RNK_RPT];
    int rank[RNK_RPT];
    int base = blockIdx.x * (256 * RNK_RPT) + tid;
    #pragma unroll
    for (int r = 0; r < RNK_RPT; ++r) {
        int e = base + r * 256;
        mine[r] = (e < PRE_NMS) ? keys[e] : 0;
        rank[r] = 0;
    }
    for (int c0 = 0; c0 < PRE_NMS; c0 += 2048) {
        for (int j = tid; j < 2048; j += 256) {
            int g = c0 + j;
            ch[j] = (g < PRE_NMS) ? keys[g] : 0;
        }
        __syncthreads();
        #pragma unroll 8
        for (int j = 0; j < 2048; ++j) {
            uint64_t kj = ch[j];
            #pragma unroll
            for (int r = 0; r < RNK_RPT; ++r) rank[r] += (kj > mine[r]) ? 1 : 0;
        }
        __syncthreads();
    }
    #pragma unroll
    for (int r = 0; r < RNK_RPT; ++r) {
        int e = base + r * 256;
        if (e < PRE_NMS) aidx[(size_t)b * PRE_NMS + rank[r]] = ~(uint32_t)(mine[r] & 0xFFFFFFFFull);
    }
}

// ---------- spatial counting-sort of ranks by (level, 64px tile Morton) ------
// Output: spat2rank[sp] = rank. Order within a tile bucket is arbitrary
// (atomic) but output of NMS is invariant to lane assignment.
__global__ __launch_bounds__(1024) void k_spatsort(const uint32_t* __restrict__ aidx,
                                                   uint32_t* __restrict__ spat2rank) {
    __shared__ uint32_t hist[2048];
    __shared__ uint32_t wsum[16];
    int b = blockIdx.x, tid = threadIdx.x;
    int wv = tid >> 6, ln = tid & 63;
    for (int i = tid; i < 2048; i += 1024) hist[i] = 0;
    __syncthreads();
    uint32_t sk[NSLOT];
    #pragma unroll
    for (int j = 0; j < NSLOT; ++j) {
        int i = tid + 1024 * j;
        sk[j] = 0;
        if (i < PRE_NMS) {
            uint32_t a = aidx[(size_t)b * PRE_NMS + i];
            uint32_t level, base, lw, sh;
            if (a < 196608)      { level = 0; base = 0;      lw = 8; sh = 2; }
            else if (a < 245760) { level = 1; base = 196608; lw = 7; sh = 3; }
            else if (a < 258048) { level = 2; base = 245760; lw = 6; sh = 4; }
            else if (a < 261120) { level = 3; base = 258048; lw = 5; sh = 5; }
            else                 { level = 4; base = 261120; lw = 4; sh = 6; }
            uint32_t cell = (a - base) / 3u;
            uint32_t x = cell & ((1u << lw) - 1u);
            uint32_t y = cell >> lw;
            uint32_t tx = (x << sh) >> 6, ty = (y << sh) >> 6;   // 0..15
            uint32_t mx = (tx | (tx << 2)) & 0x33u; mx = (mx | (mx << 1)) & 0x55u;
            uint32_t my = (ty | (ty << 2)) & 0x33u; my = (my | (my << 1)) & 0x55u;
            uint32_t key = (level << 8) | mx | (my << 1);
            sk[j] = key;
            atomicAdd(&hist[key], 1u);
        }
    }
    __syncthreads();
    // exclusive scan over 2048 bins (each thread owns 2)
    uint32_t v0 = hist[2 * tid], v1 = hist[2 * tid + 1];
    uint32_t tot = v0 + v1;
    uint32_t inc = tot;
    for (int d = 1; d < 64; d <<= 1) {
        uint32_t t = __shfl_up(inc, d);
        if (ln >= d) inc += t;
    }
    if (ln == 63) wsum[wv] = inc;
    __syncthreads();
    uint32_t wbase = 0;
    for (int w = 0; w < 16; ++w) wbase += (w < wv) ? wsum[w] : 0u;
    uint32_t excl = wbase + inc - tot;
    __syncthreads();
    hist[2 * tid] = excl;
    hist[2 * tid + 1] = excl + v0;
    __syncthreads();
    #pragma unroll
    for (int j = 0; j < NSLOT; ++j) {
        int i = tid + 1024 * j;
        if (i < PRE_NMS) {
            uint32_t pos = atomicAdd(&hist[sk[j]], 1u);
            spat2rank[(size_t)b * PRE_NMS + pos] = (uint32_t)i;
        }
    }
}

// ---------- gather + bbox decode + clip (rank order) ----------
__global__ void k_gather(const float4* __restrict__ anchors, const float4* __restrict__ deltas,
                         const float* __restrict__ im_info, const uint32_t* __restrict__ aidx,
                         float4* __restrict__ props, float* __restrict__ areas) {
    int b = blockIdx.y;
    int i = blockIdx.x * 256 + threadIdx.x;
    if (i >= PRE_NMS) return;
    uint32_t a = aidx[(size_t)b * PRE_NMS + i];
    float4 an = anchors[a];
    float4 dl = deltas[(size_t)b * NANCH + a];
    float w  = __fadd_rn(__fsub_rn(an.z, an.x), 1.0f);
    float h  = __fadd_rn(__fsub_rn(an.w, an.y), 1.0f);
    float cx = __fadd_rn(an.x, __fmul_rn(0.5f, w));
    float cy = __fadd_rn(an.y, __fmul_rn(0.5f, h));
    float pcx = __fadd_rn(__fmul_rn(dl.x, w), cx);
    float pcy = __fadd_rn(__fmul_rn(dl.y, h), cy);
    float ew = (float)exp((double)dl.z);
    float eh = (float)exp((double)dl.w);
    float pw = __fmul_rn(ew, w);
    float ph = __fmul_rn(eh, h);
    float x1 = __fsub_rn(pcx, __fmul_rn(0.5f, pw));
    float y1 = __fsub_rn(pcy, __fmul_rn(0.5f, ph));
    float x2 = __fadd_rn(pcx, __fmul_rn(0.5f, pw));
    float y2 = __fadd_rn(pcy, __fmul_rn(0.5f, ph));
    float xmax = __fsub_rn(im_info[b * 3 + 1], 1.0f);
    float ymax = __fsub_rn(im_info[b * 3 + 0], 1.0f);
    x1 = fminf(fmaxf(x1, 0.0f), xmax);
    y1 = fminf(fmaxf(y1, 0.0f), ymax);
    x2 = fminf(fmaxf(x2, 0.0f), xmax);
    y2 = fminf(fmaxf(y2, 0.0f), ymax);
    props[(size_t)b * PRE_NMS + i] = make_float4(x1, y1, x2, y2);
    areas[(size_t)b * PRE_NMS + i] =
        __fmul_rn(__fadd_rn(__fsub_rn(x2, x1), 1.0f), __fadd_rn(__fsub_rn(y2, y1), 1.0f));
}

// ---------- greedy NMS ----------
// Spatially-tiled lane assignment, rank-indexed LDS validity mask, atomic
// kills (only bits > sel ever cleared within a round; self-kill write
// skipped, scan starts at sel+1), redundant selection, ONE barrier/round.
// Exact div-free IoU test: div_rn(i,d) <= 0.7f  <=>  (double)i < MD*(double)d.
__global__ __launch_bounds__(1024) void k_nms(const float4* __restrict__ props,
                                              const float* __restrict__ areas,
                                              const uint32_t* __restrict__ s2r,
                                              float* __restrict__ out) {
    const double MD = (double)0.7f + 2.9802322387695312e-08;   // 0.7f + 2^-25
    int b = blockIdx.x;
    int tid = threadIdx.x;
    int wv = tid >> 6, ln = tid & 63;
    const float4* P = props + (size_t)b * PRE_NMS;
    const float* A = areas + (size_t)b * PRE_NMS;
    const uint32_t* SR = s2r + (size_t)b * PRE_NMS;

    __shared__ uint32_t mask[MASKW];
    __shared__ float4 gbb[16][NSLOT];     // per (wave, group): x1min,y1min,x2max+1,y2max+1
    __shared__ float4 bc[BCACHE];         // box cache for selection loads
    for (int i = tid; i < MASKW; i += 1024) mask[i] = (i < (PRE_NMS / 32)) ? 0xFFFFFFFFu : 0u;
    for (int i = tid; i < BCACHE; i += 1024) bc[i] = P[i];

    float bx1[NSLOT], by1[NSLOT], bx2[NSLOT], by2[NSLOT];
    int rr[NSLOT];
    uint32_t vm = 0;
    #pragma unroll
    for (int j = 0; j < NSLOT; ++j) {
        int sp = (wv * NSLOT + j) * 64 + ln;
        rr[j] = 0;
        bx1[j] = 1.0e30f; by1[j] = 1.0e30f; bx2[j] = -1.0e30f; by2[j] = -1.0e30f;
        if (sp < PRE_NMS) {
            int r = (int)SR[sp];
            rr[j] = r;
            float4 p = P[r];
            bx1[j] = p.x; by1[j] = p.y; bx2[j] = p.z; by2[j] = p.w;
            vm |= 1u << j;
        }
    }
    // group bboxes via wave reduction; wave bbox in registers
    float w_x1 = 1.0e30f, w_y1 = 1.0e30f, w_x2 = -1.0e30f, w_y2 = -1.0e30f;
    #pragma unroll
    for (int j = 0; j < NSLOT; ++j) {
        float a1 = bx1[j], c1 = by1[j], a2 = bx2[j], c2 = by2[j];
        for (int d = 1; d < 64; d <<= 1) {
            a1 = fminf(a1, __shfl_xor(a1, d));
            c1 = fminf(c1, __shfl_xor(c1, d));
            a2 = fmaxf(a2, __shfl_xor(a2, d));
            c2 = fmaxf(c2, __shfl_xor(c2, d));
        }
        if (ln == 0) gbb[wv][j] = make_float4(a1, c1, a2 + 1.0f, c2 + 1.0f);
        w_x1 = fminf(w_x1, a1); w_y1 = fminf(w_y1, c1);
        w_x2 = fmaxf(w_x2, a2); w_y2 = fmaxf(w_y2, c2);
    }
    w_x2 += 1.0f; w_y2 += 1.0f;

    float* outb = out + (size_t)b * POST_NMS * 5;
    int scanb = 0;
    __syncthreads();

    for (int it = 0; it < POST_NMS; ++it) {
        // ---- selection: first set bit >= scanb (identical across threads) ----
        int w = scanb >> 5;
        uint32_t word = 0u;
        if (w < MASKW) word = mask[w] & (0xFFFFFFFFu << (scanb & 31));
        while (word == 0u) {
            ++w;
            if (w >= MASKW) break;
            word = mask[w];
        }
        int sel = (word != 0u) ? ((w << 5) + __ffs(word) - 1) : -1;
        if (sel < 0) {
            for (int r = it + tid; r < POST_NMS; r += 1024) {
                float* row = outb + (size_t)r * 5;
                row[0] = (float)b; row[1] = 0.0f; row[2] = 0.0f; row[3] = 0.0f; row[4] = 0.0f;
            }
            break;
        }
        float4 sp4 = (sel < BCACHE) ? bc[sel] : P[sel];
        if (tid < 5) {
            float vout = (tid == 0) ? (float)b
                       : (tid == 1) ? sp4.x
                       : (tid == 2) ? sp4.y
                       : (tid == 3) ? sp4.z : sp4.w;
            outb[(size_t)it * 5 + tid] = vout;
        }
        float sx1 = sp4.x, sy1 = sp4.y, sx2 = sp4.z, sy2 = sp4.w;
        float sx2p = __fadd_rn(sx2, 1.0f), sy2p = __fadd_rn(sy2, 1.0f);
        // ---- wave-level empty-intersection reject ----
        if (!((w_x1 >= sx2p) || (w_x2 <= sx1) || (w_y1 >= sy2p) || (w_y2 <= sy1))) {
            float sa = A[sel];
            #pragma unroll
            for (int j = 0; j < NSLOT; ++j) {
                float4 g = gbb[wv][j];
                if ((g.x >= sx2p) || (g.z <= sx1) || (g.y >= sy2p) || (g.w <= sy1)) continue;
                bool v = (vm >> j) & 1u;
                if (v) {
                    float xx1 = fmaxf(sx1, bx1[j]);
                    float yy1 = fmaxf(sy1, by1[j]);
                    float xx2 = fminf(sx2, bx2[j]);
                    float yy2 = fminf(sy2, by2[j]);
                    float ww = fmaxf(__fadd_rn(__fsub_rn(xx2, xx1), 1.0f), 0.0f);
                    float hh = fmaxf(__fadd_rn(__fsub_rn(yy2, yy1), 1.0f), 0.0f);
                    float inter = __fmul_rn(ww, hh);
                    float ab = __fmul_rn(__fadd_rn(__fsub_rn(bx2[j], bx1[j]), 1.0f),
                                         __fadd_rn(__fsub_rn(by2[j], by1[j]), 1.0f));
                    float denom = __fsub_rn(__fadd_rn(sa, ab), inter);
                    bool kept = ((double)inter < MD * (double)denom);
                    if (!kept) {
                        vm &= ~(1u << j);
                        int r = rr[j];
                        if (r != sel) atomicAnd(&mask[r >> 5], ~(1u << (r & 31)));
                    }
                }
            }
        }
        scanb = sel + 1;
        __syncthreads();
    }
}

extern "C" void kernel_launch(void* const* d_in, const int* in_sizes, int n_in,
                              void* d_out, int out_size, void* d_ws, size_t ws_size,
                              hipStream_t stream) {
    const float* scores  = (const float*)d_in[0];
    const float* deltas  = (const float*)d_in[1];
    const float* im_info = (const float*)d_in[2];
    const float* anchors = (const float*)d_in[3];
    float* out = (float*)d_out;

    uint8_t* w = (uint8_t*)d_ws;
    uint32_t* hist      = (uint32_t*)(w);                    // 16384 B
    uint64_t* prefix    = (uint64_t*)(w + 16384);            // 128 B
    uint32_t* kth       = (uint32_t*)(w + 16512);            // 64 B
    uint32_t* cnt       = (uint32_t*)(w + 16576);            // 64 B
    uint64_t* selk      = (uint64_t*)(w + 16640);            // 1,536,000 B
    uint32_t* aidx      = (uint32_t*)(w + 1552640);          // 768,000 B
    float*    props     = (float*)(w + 2320640);             // 3,072,000 B
    float*    areas     = (float*)(w + 5392640);             // 768,000 B
    uint32_t* spat2rank = (uint32_t*)(w + 6160640);          // 768,000 B  (end 6,928,640)

    hipLaunchKernelGGL(k_init, dim3(1), dim3(1024), 0, stream, hist, prefix, kth, cnt);
    for (int p = 0; p < 8; ++p) {
        hipLaunchKernelGGL(k_hist, dim3(128, NBATCH), dim3(256), 0, stream, scores, hist, prefix, p);
        hipLaunchKernelGGL(k_pick, dim3(NBATCH), dim3(256), 0, stream, hist, prefix, kth, p);
    }
    hipLaunchKernelGGL(k_compact, dim3(128, NBATCH), dim3(256), 0, stream, scores, prefix, cnt, selk);
    hipLaunchKernelGGL(k_rank, dim3(12, NBATCH), dim3(256), 0, stream, selk, aidx);
    hipLaunchKernelGGL(k_spatsort, dim3(NBATCH), dim3(1024), 0, stream, aidx, spat2rank);
    hipLaunchKernelGGL(k_gather, dim3(47, NBATCH), dim3(256), 0, stream,
                       (const float4*)anchors, (const float4*)deltas, im_info, aidx,
                       (float4*)props, areas);
    hipLaunchKernelGGL(k_nms, dim3(NBATCH), dim3(1024), 0, stream,
                       (const float4*)props, areas, spat2rank, out);
}

// Round 3
// 3540.702 us; speedup vs baseline: 2.1727x; 1.3258x over previous
//
#include <hip/hip_runtime.h>
#include <stdint.h>
#include <math.h>

#define NANCH 261888
#define NBATCH 16
#define PRE_NMS 12000
#define POST_NMS 2000
#define NSLOT 24          // 512 threads * 24 = 12288 slots >= 12000
#define MASKW 384         // 12288 bits / 32
#define BCACHE 4096       // boxes cached in LDS for selection loads (64 KB)

// ---------- key construction: (ordered score bits << 32) | ~index ----------
__device__ __forceinline__ uint64_t make_key(float s, int i) {
    uint32_t u = __float_as_uint(s);
    u ^= (u >> 31) ? 0xFFFFFFFFu : 0x80000000u;   // total order for floats
    return ((uint64_t)u << 32) | (uint32_t)(~(uint32_t)i);
}

// ---------- init ----------
__global__ void k_init(uint32_t* hist, uint64_t* prefix, uint32_t* kth, uint32_t* cnt) {
    int tid = threadIdx.x;
    for (int i = tid; i < NBATCH * 256; i += blockDim.x) hist[i] = 0;
    if (tid < NBATCH) { prefix[tid] = 0; kth[tid] = PRE_NMS; cnt[tid] = 0; }
}

// ---------- radix-select histogram pass over 8-bit digits, MSB first ----------
__global__ void k_hist(const float* __restrict__ scores, uint32_t* __restrict__ hist,
                       const uint64_t* __restrict__ prefix, int pass) {
    __shared__ uint32_t lh[256];
    int tid = threadIdx.x;
    int b = blockIdx.y;
    lh[tid] = 0;
    __syncthreads();
    uint64_t pfx = prefix[b];
    int sp = 64 - 8 * pass;
    int sd = 56 - 8 * pass;
    const float* sc = scores + (size_t)b * NANCH;
    for (int i = blockIdx.x * 256 + tid; i < NANCH; i += gridDim.x * 256) {
        uint64_t key = make_key(sc[i], i);
        bool cand = (pass == 0) || ((key >> sp) == (pfx >> sp));
        if (cand) atomicAdd(&lh[(uint32_t)(key >> sd) & 0xFFu], 1u);
    }
    __syncthreads();
    uint32_t c = lh[tid];
    if (c) atomicAdd(&hist[b * 256 + tid], c);
}

// ---------- pick digit containing kth largest; reset hist ----------
__global__ void k_pick(uint32_t* hist, uint64_t* prefix, uint32_t* kth, int pass) {
    __shared__ uint32_t h[256];
    int tid = threadIdx.x;
    int b = blockIdx.x;
    h[tid] = hist[b * 256 + tid];
    hist[b * 256 + tid] = 0;
    __syncthreads();
    if (tid == 0) {
        uint32_t k = kth[b];
        uint32_t cum = 0;
        int d = 255;
        for (; d > 0; --d) {
            uint32_t c = h[d];
            if (cum + c >= k) break;
            cum += c;
        }
        kth[b] = k - cum;
        prefix[b] |= ((uint64_t)(uint32_t)d) << (56 - 8 * pass);
    }
}

// ---------- compact: wave-aggregated LDS staging, 1 global atomic per block ----
__global__ __launch_bounds__(256) void k_compact(const float* __restrict__ scores,
                                                 const uint64_t* __restrict__ prefix,
                                                 uint32_t* __restrict__ cnt,
                                                 uint64_t* __restrict__ selk) {
    __shared__ uint32_t lcnt, lbase;
    __shared__ uint64_t lbuf[2048];
    int tid = threadIdx.x;
    int b = blockIdx.y;
    int ln = tid & 63;
    if (tid == 0) lcnt = 0;
    __syncthreads();
    uint64_t T = prefix[b];
    const float* sc = scores + (size_t)b * NANCH;
    int base0 = blockIdx.x * 2048;
    for (int r = 0; r < 8; ++r) {
        int i = base0 + r * 256 + tid;
        bool pred = false;
        uint64_t key = 0;
        if (i < NANCH) { key = make_key(sc[i], i); pred = key >= T; }
        unsigned long long bal = __ballot(pred);
        uint32_t wb = 0;
        if (ln == 0 && bal) wb = atomicAdd(&lcnt, (uint32_t)__popcll(bal));
        wb = __shfl(wb, 0);
        if (pred) lbuf[wb + (uint32_t)__popcll(bal & ((1ull << ln) - 1ull))] = key;
    }
    __syncthreads();
    if (tid == 0) lbase = atomicAdd(&cnt[b], lcnt);
    __syncthreads();
    uint32_t n = lcnt, bs = lbase;
    for (uint32_t i = tid; i < n; i += 256) {
        uint32_t p = bs + i;
        if (p < PRE_NMS) selk[(size_t)b * PRE_NMS + p] = lbuf[i];
    }
}

// ---------- rank sort: rank = #{keys > mine}; scatter anchor idx to rank -----
#define RNK_RPT 4
__global__ void k_rank(const uint64_t* __restrict__ selk, uint32_t* __restrict__ aidx) {
    __shared__ uint64_t ch[2048];
    int tid = threadIdx.x;
    int b = blockIdx.y;
    const uint64_t* keys = selk + (size_t)b * PRE_NMS;
    uint64_t mine[RNK_RPT];
    int rank[RNK_RPT];
    int base = blockIdx.x * (256 * RNK_RPT) + tid;
    #pragma unroll
    for (int r = 0; r < RNK_RPT; ++r) {
        int e = base + r * 256;
        mine[r] = (e < PRE_NMS) ? keys[e] : 0;
        rank[r] = 0;
    }
    for (int c0 = 0; c0 < PRE_NMS; c0 += 2048) {
        for (int j = tid; j < 2048; j += 256) {
            int g = c0 + j;
            ch[j] = (g < PRE_NMS) ? keys[g] : 0;
        }
        __syncthreads();
        #pragma unroll 8
        for (int j = 0; j < 2048; ++j) {
            uint64_t kj = ch[j];
            #pragma unroll
            for (int r = 0; r < RNK_RPT; ++r) rank[r] += (kj > mine[r]) ? 1 : 0;
        }
        __syncthreads();
    }
    #pragma unroll
    for (int r = 0; r < RNK_RPT; ++r) {
        int e = base + r * 256;
        if (e < PRE_NMS) aidx[(size_t)b * PRE_NMS + rank[r]] = ~(uint32_t)(mine[r] & 0xFFFFFFFFull);
    }
}

// ---------- spatial counting-sort of ranks by (level, 64px tile Morton) ------
__global__ __launch_bounds__(1024) void k_spatsort(const uint32_t* __restrict__ aidx,
                                                   uint32_t* __restrict__ spat2rank) {
    __shared__ uint32_t hist[2048];
    __shared__ uint32_t wsum[16];
    int b = blockIdx.x, tid = threadIdx.x;
    int wv = tid >> 6, ln = tid & 63;
    for (int i = tid; i < 2048; i += 1024) hist[i] = 0;
    __syncthreads();
    uint32_t sk[12];
    #pragma unroll
    for (int j = 0; j < 12; ++j) {
        int i = tid + 1024 * j;
        sk[j] = 0;
        if (i < PRE_NMS) {
            uint32_t a = aidx[(size_t)b * PRE_NMS + i];
            uint32_t level, base, lw, sh;
            if (a < 196608)      { level = 0; base = 0;      lw = 8; sh = 2; }
            else if (a < 245760) { level = 1; base = 196608; lw = 7; sh = 3; }
            else if (a < 258048) { level = 2; base = 245760; lw = 6; sh = 4; }
            else if (a < 261120) { level = 3; base = 258048; lw = 5; sh = 5; }
            else                 { level = 4; base = 261120; lw = 4; sh = 6; }
            uint32_t cell = (a - base) / 3u;
            uint32_t x = cell & ((1u << lw) - 1u);
            uint32_t y = cell >> lw;
            uint32_t tx = (x << sh) >> 6, ty = (y << sh) >> 6;   // 0..15
            uint32_t mx = (tx | (tx << 2)) & 0x33u; mx = (mx | (mx << 1)) & 0x55u;
            uint32_t my = (ty | (ty << 2)) & 0x33u; my = (my | (my << 1)) & 0x55u;
            uint32_t key = (level << 8) | mx | (my << 1);
            sk[j] = key;
            atomicAdd(&hist[key], 1u);
        }
    }
    __syncthreads();
    uint32_t v0 = hist[2 * tid], v1 = hist[2 * tid + 1];
    uint32_t tot = v0 + v1;
    uint32_t inc = tot;
    for (int d = 1; d < 64; d <<= 1) {
        uint32_t t = __shfl_up(inc, d);
        if (ln >= d) inc += t;
    }
    if (ln == 63) wsum[wv] = inc;
    __syncthreads();
    uint32_t wbase = 0;
    for (int w = 0; w < 16; ++w) wbase += (w < wv) ? wsum[w] : 0u;
    uint32_t excl = wbase + inc - tot;
    __syncthreads();
    hist[2 * tid] = excl;
    hist[2 * tid + 1] = excl + v0;
    __syncthreads();
    #pragma unroll
    for (int j = 0; j < 12; ++j) {
        int i = tid + 1024 * j;
        if (i < PRE_NMS) {
            uint32_t pos = atomicAdd(&hist[sk[j]], 1u);
            spat2rank[(size_t)b * PRE_NMS + pos] = (uint32_t)i;
        }
    }
}

// ---------- gather + bbox decode + clip (rank order) ----------
__global__ void k_gather(const float4* __restrict__ anchors, const float4* __restrict__ deltas,
                         const float* __restrict__ im_info, const uint32_t* __restrict__ aidx,
                         float4* __restrict__ props, float* __restrict__ areas) {
    int b = blockIdx.y;
    int i = blockIdx.x * 256 + threadIdx.x;
    if (i >= PRE_NMS) return;
    uint32_t a = aidx[(size_t)b * PRE_NMS + i];
    float4 an = anchors[a];
    float4 dl = deltas[(size_t)b * NANCH + a];
    float w  = __fadd_rn(__fsub_rn(an.z, an.x), 1.0f);
    float h  = __fadd_rn(__fsub_rn(an.w, an.y), 1.0f);
    float cx = __fadd_rn(an.x, __fmul_rn(0.5f, w));
    float cy = __fadd_rn(an.y, __fmul_rn(0.5f, h));
    float pcx = __fadd_rn(__fmul_rn(dl.x, w), cx);
    float pcy = __fadd_rn(__fmul_rn(dl.y, h), cy);
    float ew = (float)exp((double)dl.z);
    float eh = (float)exp((double)dl.w);
    float pw = __fmul_rn(ew, w);
    float ph = __fmul_rn(eh, h);
    float x1 = __fsub_rn(pcx, __fmul_rn(0.5f, pw));
    float y1 = __fsub_rn(pcy, __fmul_rn(0.5f, ph));
    float x2 = __fadd_rn(pcx, __fmul_rn(0.5f, pw));
    float y2 = __fadd_rn(pcy, __fmul_rn(0.5f, ph));
    float xmax = __fsub_rn(im_info[b * 3 + 1], 1.0f);
    float ymax = __fsub_rn(im_info[b * 3 + 0], 1.0f);
    x1 = fminf(fmaxf(x1, 0.0f), xmax);
    y1 = fminf(fmaxf(y1, 0.0f), ymax);
    x2 = fminf(fmaxf(x2, 0.0f), xmax);
    y2 = fminf(fmaxf(y2, 0.0f), ymax);
    props[(size_t)b * PRE_NMS + i] = make_float4(x1, y1, x2, y2);
    areas[(size_t)b * PRE_NMS + i] =
        __fmul_rn(__fadd_rn(__fsub_rn(x2, x1), 1.0f), __fadd_rn(__fsub_rn(y2, y1), 1.0f));
}

// ---------- greedy NMS: 8 waves x 24 slots, register group-bboxes + ballot ----
// Invariants (proven r2): current-round kills only clear rank bits > sel
// (self-kill skipped), so concurrent scan/kill is race-free with one barrier
// per round. Exact div-free IoU: div_rn(i,d) <= 0.7f <=> (double)i < MD*(double)d.
__global__ __launch_bounds__(512, 2) void k_nms(const float4* __restrict__ props,
                                                const uint32_t* __restrict__ s2r,
                                                float* __restrict__ out) {
    const double MD = (double)0.7f + 2.9802322387695312e-08;   // 0.7f + 2^-25
    int b = blockIdx.x;
    int tid = threadIdx.x;
    int wv = tid >> 6, ln = tid & 63;
    const float4* P = props + (size_t)b * PRE_NMS;
    const uint32_t* SR = s2r + (size_t)b * PRE_NMS;

    __shared__ uint32_t mask[MASKW];
    __shared__ float4 bc[BCACHE];
    for (int i = tid; i < MASKW; i += 512) mask[i] = (i < (PRE_NMS / 32)) ? 0xFFFFFFFFu : 0u;
    for (int i = tid; i < BCACHE; i += 512) bc[i] = P[i];

    float bx1[NSLOT], by1[NSLOT], bx2[NSLOT], by2[NSLOT], bar[NSLOT];
    int rr[NSLOT];
    uint32_t vm = 0;
    #pragma unroll
    for (int j = 0; j < NSLOT; ++j) {
        int sp = (wv * NSLOT + j) * 64 + ln;
        rr[j] = 0; bar[j] = 1.0f;
        bx1[j] = 1.0e30f; by1[j] = 1.0e30f; bx2[j] = -1.0e30f; by2[j] = -1.0e30f;
        if (sp < PRE_NMS) {
            int r = (int)SR[sp];
            rr[j] = r;
            float4 p = P[r];
            bx1[j] = p.x; by1[j] = p.y; bx2[j] = p.z; by2[j] = p.w;
            bar[j] = __fmul_rn(__fadd_rn(__fsub_rn(p.z, p.x), 1.0f),
                               __fadd_rn(__fsub_rn(p.w, p.y), 1.0f));
            vm |= 1u << j;
        }
    }
    // lane g (g < NSLOT) keeps group g's bbox (x1min, y1min, x2max+1, y2max+1)
    float gx1 = 1.0e30f, gy1 = 1.0e30f, gx2p = -1.0e30f, gy2p = -1.0e30f;
    float w_x1 = 1.0e30f, w_y1 = 1.0e30f, w_x2 = -1.0e30f, w_y2 = -1.0e30f;
    #pragma unroll
    for (int j = 0; j < NSLOT; ++j) {
        float a1 = bx1[j], c1 = by1[j], a2 = bx2[j], c2 = by2[j];
        for (int d = 1; d < 64; d <<= 1) {
            a1 = fminf(a1, __shfl_xor(a1, d));
            c1 = fminf(c1, __shfl_xor(c1, d));
            a2 = fmaxf(a2, __shfl_xor(a2, d));
            c2 = fmaxf(c2, __shfl_xor(c2, d));
        }
        if (ln == j) { gx1 = a1; gy1 = c1; gx2p = a2 + 1.0f; gy2p = c2 + 1.0f; }
        w_x1 = fminf(w_x1, a1); w_y1 = fminf(w_y1, c1);
        w_x2 = fmaxf(w_x2, a2); w_y2 = fmaxf(w_y2, c2);
    }
    w_x2 += 1.0f; w_y2 += 1.0f;

    float* outb = out + (size_t)b * POST_NMS * 5;
    int scanb = 0;
    __syncthreads();

    for (int it = 0; it < POST_NMS; ++it) {
        // ---- lane-parallel scan: first set bit >= scanb (1 LDS read typical) --
        int w0 = scanb >> 5;
        int sel = -1;
        while (w0 < MASKW) {
            int w = w0 + ln;
            uint32_t wd = (w < MASKW) ? mask[w] : 0u;
            if (w == (scanb >> 5)) wd &= (0xFFFFFFFFu << (scanb & 31));
            unsigned long long bal = __ballot(wd != 0u);
            if (bal) {
                int L = __ffsll((unsigned long long)bal) - 1;
                uint32_t wsel = __shfl(wd, L);
                sel = ((w0 + L) << 5) + __ffs(wsel) - 1;
                break;
            }
            w0 += 64;
        }
        if (sel < 0) {
            for (int r2 = it + tid; r2 < POST_NMS; r2 += 512) {
                float* row = outb + (size_t)r2 * 5;
                row[0] = (float)b; row[1] = 0.0f; row[2] = 0.0f; row[3] = 0.0f; row[4] = 0.0f;
            }
            break;
        }
        float4 sp4 = (sel < BCACHE) ? bc[sel] : P[sel];
        if (tid < 5) {
            float vout = (tid == 0) ? (float)b
                       : (tid == 1) ? sp4.x
                       : (tid == 2) ? sp4.y
                       : (tid == 3) ? sp4.z : sp4.w;
            outb[(size_t)it * 5 + tid] = vout;
        }
        float sx1 = sp4.x, sy1 = sp4.y, sx2 = sp4.z, sy2 = sp4.w;
        float sx2p = __fadd_rn(sx2, 1.0f), sy2p = __fadd_rn(sy2, 1.0f);
        scanb = sel + 1;
        // ---- wave-level empty-intersection reject ----
        if (!((w_x1 >= sx2p) || (w_x2 <= sx1) || (w_y1 >= sy2p) || (w_y2 <= sy1))) {
            float sa = __fmul_rn(__fadd_rn(__fsub_rn(sx2, sx1), 1.0f),
                                 __fadd_rn(__fsub_rn(sy2, sy1), 1.0f));
            // register group-bbox test, one ballot -> wave-uniform todo mask
            bool ovl = (ln < NSLOT) &&
                       !((gx1 >= sx2p) || (gx2p <= sx1) || (gy1 >= sy2p) || (gy2p <= sy1));
            unsigned long long todo = __ballot(ovl);
            #pragma unroll
            for (int j = 0; j < NSLOT; ++j) {
                if (todo & (1ull << j)) {           // wave-uniform -> scalar branch
                    if ((vm >> j) & 1u) {
                        float xx1 = fmaxf(sx1, bx1[j]);
                        float yy1 = fmaxf(sy1, by1[j]);
                        float xx2 = fminf(sx2, bx2[j]);
                        float yy2 = fminf(sy2, by2[j]);
                        float ww2 = fmaxf(__fadd_rn(__fsub_rn(xx2, xx1), 1.0f), 0.0f);
                        float hh2 = fmaxf(__fadd_rn(__fsub_rn(yy2, yy1), 1.0f), 0.0f);
                        float inter = __fmul_rn(ww2, hh2);
                        float denom = __fsub_rn(__fadd_rn(sa, bar[j]), inter);
                        if (!((double)inter < MD * (double)denom)) {
                            vm &= ~(1u << j);
                            int r = rr[j];
                            if (r != sel) atomicAnd(&mask[r >> 5], ~(1u << (r & 31)));
                        }
                    }
                }
            }
        }
        __syncthreads();
    }
}

extern "C" void kernel_launch(void* const* d_in, const int* in_sizes, int n_in,
                              void* d_out, int out_size, void* d_ws, size_t ws_size,
                              hipStream_t stream) {
    const float* scores  = (const float*)d_in[0];
    const float* deltas  = (const float*)d_in[1];
    const float* im_info = (const float*)d_in[2];
    const float* anchors = (const float*)d_in[3];
    float* out = (float*)d_out;

    uint8_t* w = (uint8_t*)d_ws;
    uint32_t* hist      = (uint32_t*)(w);                    // 16384 B
    uint64_t* prefix    = (uint64_t*)(w + 16384);            // 128 B
    uint32_t* kth       = (uint32_t*)(w + 16512);            // 64 B
    uint32_t* cnt       = (uint32_t*)(w + 16576);            // 64 B
    uint64_t* selk      = (uint64_t*)(w + 16640);            // 1,536,000 B
    uint32_t* aidx      = (uint32_t*)(w + 1552640);          // 768,000 B
    float*    props     = (float*)(w + 2320640);             // 3,072,000 B
    float*    areas     = (float*)(w + 5392640);             // 768,000 B
    uint32_t* spat2rank = (uint32_t*)(w + 6160640);          // 768,000 B  (end 6,928,640)

    hipLaunchKernelGGL(k_init, dim3(1), dim3(1024), 0, stream, hist, prefix, kth, cnt);
    for (int p = 0; p < 8; ++p) {
        hipLaunchKernelGGL(k_hist, dim3(128, NBATCH), dim3(256), 0, stream, scores, hist, prefix, p);
        hipLaunchKernelGGL(k_pick, dim3(NBATCH), dim3(256), 0, stream, hist, prefix, kth, p);
    }
    hipLaunchKernelGGL(k_compact, dim3(128, NBATCH), dim3(256), 0, stream, scores, prefix, cnt, selk);
    hipLaunchKernelGGL(k_rank, dim3(12, NBATCH), dim3(256), 0, stream, selk, aidx);
    hipLaunchKernelGGL(k_spatsort, dim3(NBATCH), dim3(1024), 0, stream, aidx, spat2rank);
    hipLaunchKernelGGL(k_gather, dim3(47, NBATCH), dim3(256), 0, stream,
                       (const float4*)anchors, (const float4*)deltas, im_info, aidx,
                       (float4*)props, areas);
    hipLaunchKernelGGL(k_nms, dim3(NBATCH), dim3(512), 0, stream,
                       (const float4*)props, spat2rank, out);
}

// Round 4
// 3335.184 us; speedup vs baseline: 2.3065x; 1.0616x over previous
//
#include <hip/hip_runtime.h>
#include <stdint.h>
#include <math.h>

#define NANCH 261888
#define NBATCH 16
#define PRE_NMS 12000
#define POST_NMS 2000
#define NSLOT 24          // 512 threads * 24 = 12288 slots >= 12000
#define MASKW 384         // 12288 bits / 32
#define BCACHE 9216       // boxes cached in LDS (144 KB); mask 1.5 KB -> 149 KB total

// ---------- key construction: (ordered score bits << 32) | ~index ----------
__device__ __forceinline__ uint64_t make_key(float s, int i) {
    uint32_t u = __float_as_uint(s);
    u ^= (u >> 31) ? 0xFFFFFFFFu : 0x80000000u;   // total order for floats
    return ((uint64_t)u << 32) | (uint32_t)(~(uint32_t)i);
}

// ---------- init ----------
__global__ void k_init(uint32_t* hist, uint64_t* prefix, uint32_t* kth, uint32_t* cnt) {
    int tid = threadIdx.x;
    for (int i = tid; i < NBATCH * 256; i += blockDim.x) hist[i] = 0;
    if (tid < NBATCH) { prefix[tid] = 0; kth[tid] = PRE_NMS; cnt[tid] = 0; }
}

// ---------- radix-select histogram pass over 8-bit digits, MSB first ----------
__global__ void k_hist(const float* __restrict__ scores, uint32_t* __restrict__ hist,
                       const uint64_t* __restrict__ prefix, int pass) {
    __shared__ uint32_t lh[256];
    int tid = threadIdx.x;
    int b = blockIdx.y;
    lh[tid] = 0;
    __syncthreads();
    uint64_t pfx = prefix[b];
    int sp = 64 - 8 * pass;
    int sd = 56 - 8 * pass;
    const float* sc = scores + (size_t)b * NANCH;
    for (int i = blockIdx.x * 256 + tid; i < NANCH; i += gridDim.x * 256) {
        uint64_t key = make_key(sc[i], i);
        bool cand = (pass == 0) || ((key >> sp) == (pfx >> sp));
        if (cand) atomicAdd(&lh[(uint32_t)(key >> sd) & 0xFFu], 1u);
    }
    __syncthreads();
    uint32_t c = lh[tid];
    if (c) atomicAdd(&hist[b * 256 + tid], c);
}

// ---------- pick digit containing kth largest; reset hist ----------
__global__ void k_pick(uint32_t* hist, uint64_t* prefix, uint32_t* kth, int pass) {
    __shared__ uint32_t h[256];
    int tid = threadIdx.x;
    int b = blockIdx.x;
    h[tid] = hist[b * 256 + tid];
    hist[b * 256 + tid] = 0;
    __syncthreads();
    if (tid == 0) {
        uint32_t k = kth[b];
        uint32_t cum = 0;
        int d = 255;
        for (; d > 0; --d) {
            uint32_t c = h[d];
            if (cum + c >= k) break;
            cum += c;
        }
        kth[b] = k - cum;
        prefix[b] |= ((uint64_t)(uint32_t)d) << (56 - 8 * pass);
    }
}

// ---------- compact: wave-aggregated LDS staging, 1 global atomic per block ----
__global__ __launch_bounds__(256) void k_compact(const float* __restrict__ scores,
                                                 const uint64_t* __restrict__ prefix,
                                                 uint32_t* __restrict__ cnt,
                                                 uint64_t* __restrict__ selk) {
    __shared__ uint32_t lcnt, lbase;
    __shared__ uint64_t lbuf[2048];
    int tid = threadIdx.x;
    int b = blockIdx.y;
    int ln = tid & 63;
    if (tid == 0) lcnt = 0;
    __syncthreads();
    uint64_t T = prefix[b];
    const float* sc = scores + (size_t)b * NANCH;
    int base0 = blockIdx.x * 2048;
    for (int r = 0; r < 8; ++r) {
        int i = base0 + r * 256 + tid;
        bool pred = false;
        uint64_t key = 0;
        if (i < NANCH) { key = make_key(sc[i], i); pred = key >= T; }
        unsigned long long bal = __ballot(pred);
        uint32_t wb = 0;
        if (ln == 0 && bal) wb = atomicAdd(&lcnt, (uint32_t)__popcll(bal));
        wb = __shfl(wb, 0);
        if (pred) lbuf[wb + (uint32_t)__popcll(bal & ((1ull << ln) - 1ull))] = key;
    }
    __syncthreads();
    if (tid == 0) lbase = atomicAdd(&cnt[b], lcnt);
    __syncthreads();
    uint32_t n = lcnt, bs = lbase;
    for (uint32_t i = tid; i < n; i += 256) {
        uint32_t p = bs + i;
        if (p < PRE_NMS) selk[(size_t)b * PRE_NMS + p] = lbuf[i];
    }
}

// ---------- rank sort: rank = #{keys > mine}; scatter anchor idx to rank -----
#define RNK_RPT 4
__global__ void k_rank(const uint64_t* __restrict__ selk, uint32_t* __restrict__ aidx) {
    __shared__ uint64_t ch[2048];
    int tid = threadIdx.x;
    int b = blockIdx.y;
    const uint64_t* keys = selk + (size_t)b * PRE_NMS;
    uint64_t mine[RNK_RPT];
    int rank[RNK_RPT];
    int base = blockIdx.x * (256 * RNK_RPT) + tid;
    #pragma unroll
    for (int r = 0; r < RNK_RPT; ++r) {
        int e = base + r * 256;
        mine[r] = (e < PRE_NMS) ? keys[e] : 0;
        rank[r] = 0;
    }
    for (int c0 = 0; c0 < PRE_NMS; c0 += 2048) {
        for (int j = tid; j < 2048; j += 256) {
            int g = c0 + j;
            ch[j] = (g < PRE_NMS) ? keys[g] : 0;
        }
        __syncthreads();
        #pragma unroll 8
        for (int j = 0; j < 2048; ++j) {
            uint64_t kj = ch[j];
            #pragma unroll
            for (int r = 0; r < RNK_RPT; ++r) rank[r] += (kj > mine[r]) ? 1 : 0;
        }
        __syncthreads();
    }
    #pragma unroll
    for (int r = 0; r < RNK_RPT; ++r) {
        int e = base + r * 256;
        if (e < PRE_NMS) aidx[(size_t)b * PRE_NMS + rank[r]] = ~(uint32_t)(mine[r] & 0xFFFFFFFFull);
    }
}

// ---------- spatial counting-sort of ranks by (level, 64px tile Morton) ------
__global__ __launch_bounds__(1024) void k_spatsort(const uint32_t* __restrict__ aidx,
                                                   uint32_t* __restrict__ spat2rank) {
    __shared__ uint32_t hist[2048];
    __shared__ uint32_t wsum[16];
    int b = blockIdx.x, tid = threadIdx.x;
    int wv = tid >> 6, ln = tid & 63;
    for (int i = tid; i < 2048; i += 1024) hist[i] = 0;
    __syncthreads();
    uint32_t sk[12];
    #pragma unroll
    for (int j = 0; j < 12; ++j) {
        int i = tid + 1024 * j;
        sk[j] = 0;
        if (i < PRE_NMS) {
            uint32_t a = aidx[(size_t)b * PRE_NMS + i];
            uint32_t level, base, lw, sh;
            if (a < 196608)      { level = 0; base = 0;      lw = 8; sh = 2; }
            else if (a < 245760) { level = 1; base = 196608; lw = 7; sh = 3; }
            else if (a < 258048) { level = 2; base = 245760; lw = 6; sh = 4; }
            else if (a < 261120) { level = 3; base = 258048; lw = 5; sh = 5; }
            else                 { level = 4; base = 261120; lw = 4; sh = 6; }
            uint32_t cell = (a - base) / 3u;
            uint32_t x = cell & ((1u << lw) - 1u);
            uint32_t y = cell >> lw;
            uint32_t tx = (x << sh) >> 6, ty = (y << sh) >> 6;   // 0..15
            uint32_t mx = (tx | (tx << 2)) & 0x33u; mx = (mx | (mx << 1)) & 0x55u;
            uint32_t my = (ty | (ty << 2)) & 0x33u; my = (my | (my << 1)) & 0x55u;
            uint32_t key = (level << 8) | mx | (my << 1);
            sk[j] = key;
            atomicAdd(&hist[key], 1u);
        }
    }
    __syncthreads();
    uint32_t v0 = hist[2 * tid], v1 = hist[2 * tid + 1];
    uint32_t tot = v0 + v1;
    uint32_t inc = tot;
    for (int d = 1; d < 64; d <<= 1) {
        uint32_t t = __shfl_up(inc, d);
        if (ln >= d) inc += t;
    }
    if (ln == 63) wsum[wv] = inc;
    __syncthreads();
    uint32_t wbase = 0;
    for (int w = 0; w < 16; ++w) wbase += (w < wv) ? wsum[w] : 0u;
    uint32_t excl = wbase + inc - tot;
    __syncthreads();
    hist[2 * tid] = excl;
    hist[2 * tid + 1] = excl + v0;
    __syncthreads();
    #pragma unroll
    for (int j = 0; j < 12; ++j) {
        int i = tid + 1024 * j;
        if (i < PRE_NMS) {
            uint32_t pos = atomicAdd(&hist[sk[j]], 1u);
            spat2rank[(size_t)b * PRE_NMS + pos] = (uint32_t)i;
        }
    }
}

// ---------- gather + bbox decode + clip (rank order) ----------
__global__ void k_gather(const float4* __restrict__ anchors, const float4* __restrict__ deltas,
                         const float* __restrict__ im_info, const uint32_t* __restrict__ aidx,
                         float4* __restrict__ props) {
    int b = blockIdx.y;
    int i = blockIdx.x * 256 + threadIdx.x;
    if (i >= PRE_NMS) return;
    uint32_t a = aidx[(size_t)b * PRE_NMS + i];
    float4 an = anchors[a];
    float4 dl = deltas[(size_t)b * NANCH + a];
    float w  = __fadd_rn(__fsub_rn(an.z, an.x), 1.0f);
    float h  = __fadd_rn(__fsub_rn(an.w, an.y), 1.0f);
    float cx = __fadd_rn(an.x, __fmul_rn(0.5f, w));
    float cy = __fadd_rn(an.y, __fmul_rn(0.5f, h));
    float pcx = __fadd_rn(__fmul_rn(dl.x, w), cx);
    float pcy = __fadd_rn(__fmul_rn(dl.y, h), cy);
    float ew = (float)exp((double)dl.z);
    float eh = (float)exp((double)dl.w);
    float pw = __fmul_rn(ew, w);
    float ph = __fmul_rn(eh, h);
    float x1 = __fsub_rn(pcx, __fmul_rn(0.5f, pw));
    float y1 = __fsub_rn(pcy, __fmul_rn(0.5f, ph));
    float x2 = __fadd_rn(pcx, __fmul_rn(0.5f, pw));
    float y2 = __fadd_rn(pcy, __fmul_rn(0.5f, ph));
    float xmax = __fsub_rn(im_info[b * 3 + 1], 1.0f);
    float ymax = __fsub_rn(im_info[b * 3 + 0], 1.0f);
    x1 = fminf(fmaxf(x1, 0.0f), xmax);
    y1 = fminf(fmaxf(y1, 0.0f), ymax);
    x2 = fminf(fmaxf(x2, 0.0f), xmax);
    y2 = fminf(fmaxf(y2, 0.0f), ymax);
    props[(size_t)b * PRE_NMS + i] = make_float4(x1, y1, x2, y2);
}

// ---------- greedy NMS: 8 waves x 24 slots, K=2 selections per barrier -------
// Determinism/race proof (r2..r4): current-round kills only clear rank bits
// that every redundant walker would reject identically via the exact IoU test
// (all bits in (s0,s1) fail vs s0 by definition of "first survivor"); bits s0,
// s1 are never cleared. One barrier covers both selections.
// Exact div-free IoU: div_rn(i,d) <= 0.7f  <=>  (double)i < MD*(double)d.
__global__ __launch_bounds__(512) void k_nms(const float4* __restrict__ props,
                                             const uint32_t* __restrict__ s2r,
                                             float* __restrict__ out) {
    const double MD = (double)0.7f + 2.9802322387695312e-08;   // 0.7f + 2^-25
    int b = blockIdx.x;
    int tid = threadIdx.x;
    int wv = tid >> 6, ln = tid & 63;
    const float4* P = props + (size_t)b * PRE_NMS;
    const uint32_t* SR = s2r + (size_t)b * PRE_NMS;

    __shared__ uint32_t mask[MASKW];
    __shared__ float4 bc[BCACHE];
    for (int i = tid; i < MASKW; i += 512) mask[i] = (i < (PRE_NMS / 32)) ? 0xFFFFFFFFu : 0u;
    for (int i = tid; i < BCACHE; i += 512) bc[i] = P[i];

    float bx1[NSLOT], by1[NSLOT], bx2[NSLOT], by2[NSLOT];
    uint32_t rrp[NSLOT / 2];   // packed ranks, 2 x u16 per reg
    uint32_t vm = 0;
    #pragma unroll
    for (int j = 0; j < NSLOT / 2; ++j) rrp[j] = 0;
    #pragma unroll
    for (int j = 0; j < NSLOT; ++j) {
        int sp = (wv * NSLOT + j) * 64 + ln;
        bx1[j] = 1.0e30f; by1[j] = 1.0e30f; bx2[j] = -1.0e30f; by2[j] = -1.0e30f;
        if (sp < PRE_NMS) {
            int r = (int)SR[sp];
            rrp[j >> 1] |= ((uint32_t)r) << ((j & 1) * 16);
            float4 p = P[r];
            bx1[j] = p.x; by1[j] = p.y; bx2[j] = p.z; by2[j] = p.w;
            vm |= 1u << j;
        }
    }
    // lane g (g < NSLOT) keeps group g's bbox (x1min, y1min, x2max+1, y2max+1)
    float gx1 = 1.0e30f, gy1 = 1.0e30f, gx2p = -1.0e30f, gy2p = -1.0e30f;
    #pragma unroll
    for (int j = 0; j < NSLOT; ++j) {
        float a1 = bx1[j], c1 = by1[j], a2 = bx2[j], c2 = by2[j];
        for (int d = 1; d < 64; d <<= 1) {
            a1 = fminf(a1, __shfl_xor(a1, d));
            c1 = fminf(c1, __shfl_xor(c1, d));
            a2 = fmaxf(a2, __shfl_xor(a2, d));
            c2 = fmaxf(c2, __shfl_xor(c2, d));
        }
        if (ln == j) { gx1 = a1; gy1 = c1; gx2p = a2 + 1.0f; gy2p = c2 + 1.0f; }
    }

    float* outb = out + (size_t)b * POST_NMS * 5;
    int scanb = 0;
    __syncthreads();

    // exact kill test of slot j vs box (qx1..qy2, area qa); true = kill
    auto kill_test = [&](float qx1, float qy1, float qx2, float qy2, float qa, int j) -> bool {
        float xx1 = fmaxf(qx1, bx1[j]);
        float yy1 = fmaxf(qy1, by1[j]);
        float xx2 = fminf(qx2, bx2[j]);
        float yy2 = fminf(qy2, by2[j]);
        float ww2 = fmaxf(__fadd_rn(__fsub_rn(xx2, xx1), 1.0f), 0.0f);
        float hh2 = fmaxf(__fadd_rn(__fsub_rn(yy2, yy1), 1.0f), 0.0f);
        float inter = __fmul_rn(ww2, hh2);
        float ab = __fmul_rn(__fadd_rn(__fsub_rn(bx2[j], bx1[j]), 1.0f),
                             __fadd_rn(__fsub_rn(by2[j], by1[j]), 1.0f));
        float denom = __fsub_rn(__fadd_rn(qa, ab), inter);
        return !((double)inter < MD * (double)denom);
    };

    int it = 0;
    while (it < POST_NMS) {
        // ---- scan: load 64-word window, find s0 ----
        int w0 = scanb >> 5;
        uint32_t wd;
        {
            int w = w0 + ln;
            wd = (w < MASKW) ? mask[w] : 0u;
            if (ln == 0) wd &= (0xFFFFFFFFu << (scanb & 31));
        }
        int s0 = -1;
        while (true) {
            unsigned long long bal = __ballot(wd != 0u);
            if (bal) {
                int L = __ffsll(bal) - 1;
                uint32_t wsel = (uint32_t)__builtin_amdgcn_readlane((int)wd, L);
                s0 = ((w0 + L) << 5) + (__ffs(wsel) - 1);
                if (ln == L) wd &= (wd - 1);   // drop s0 from window for the walk
                break;
            }
            w0 += 64;
            if (w0 >= MASKW) break;
            int w = w0 + ln;
            wd = (w < MASKW) ? mask[w] : 0u;
        }
        if (s0 < 0) {
            for (int r2 = it + tid; r2 < POST_NMS; r2 += 512) {
                float* row = outb + (size_t)r2 * 5;
                row[0] = (float)b; row[1] = 0.0f; row[2] = 0.0f; row[3] = 0.0f; row[4] = 0.0f;
            }
            break;
        }
        float4 sp0 = (s0 < BCACHE) ? bc[s0] : P[s0];
        float s0a = __fmul_rn(__fadd_rn(__fsub_rn(sp0.z, sp0.x), 1.0f),
                              __fadd_rn(__fsub_rn(sp0.w, sp0.y), 1.0f));
        // ---- walk the register window for s1 = first survivor of s0 ----
        int s1 = -1;
        float4 sp1 = sp0;
        float s1a = 0.0f;
        if (it + 1 < POST_NMS) {
            while (true) {
                unsigned long long bal = __ballot(wd != 0u);
                if (!bal) break;
                int L = __ffsll(bal) - 1;
                uint32_t wsel = (uint32_t)__builtin_amdgcn_readlane((int)wd, L);
                int c = ((w0 + L) << 5) + (__ffs(wsel) - 1);
                float4 pc = (c < BCACHE) ? bc[c] : P[c];
                float xx1 = fmaxf(sp0.x, pc.x);
                float yy1 = fmaxf(sp0.y, pc.y);
                float xx2 = fminf(sp0.z, pc.z);
                float yy2 = fminf(sp0.w, pc.w);
                float ww2 = fmaxf(__fadd_rn(__fsub_rn(xx2, xx1), 1.0f), 0.0f);
                float hh2 = fmaxf(__fadd_rn(__fsub_rn(yy2, yy1), 1.0f), 0.0f);
                float inter = __fmul_rn(ww2, hh2);
                float ca = __fmul_rn(__fadd_rn(__fsub_rn(pc.z, pc.x), 1.0f),
                                     __fadd_rn(__fsub_rn(pc.w, pc.y), 1.0f));
                float denom = __fsub_rn(__fadd_rn(s0a, ca), inter);
                if ((double)inter < MD * (double)denom) {
                    s1 = c; sp1 = pc;
                    s1a = ca;
                    break;
                }
                if (ln == L) wd &= (wd - 1);   // candidate killed by s0; next
            }
        }
        // ---- output rows ----
        if (tid < 5) {
            float vout = (tid == 0) ? (float)b
                       : (tid == 1) ? sp0.x
                       : (tid == 2) ? sp0.y
                       : (tid == 3) ? sp0.z : sp0.w;
            outb[(size_t)it * 5 + tid] = vout;
        }
        if (s1 >= 0 && tid >= 5 && tid < 10) {
            int t5 = tid - 5;
            float vout = (t5 == 0) ? (float)b
                       : (t5 == 1) ? sp1.x
                       : (t5 == 2) ? sp1.y
                       : (t5 == 3) ? sp1.z : sp1.w;
            outb[(size_t)(it + 1) * 5 + t5] = vout;
        }
        // ---- kills vs s0 and s1 (register group bboxes + ballot) ----
        float s0x2p = __fadd_rn(sp0.z, 1.0f), s0y2p = __fadd_rn(sp0.w, 1.0f);
        float s1x2p = __fadd_rn(sp1.z, 1.0f), s1y2p = __fadd_rn(sp1.w, 1.0f);
        bool ovl0 = (ln < NSLOT) &&
                    !((gx1 >= s0x2p) || (gx2p <= sp0.x) || (gy1 >= s0y2p) || (gy2p <= sp0.y));
        bool ovl1 = (s1 >= 0) && (ln < NSLOT) &&
                    !((gx1 >= s1x2p) || (gx2p <= sp1.x) || (gy1 >= s1y2p) || (gy2p <= sp1.y));
        uint32_t todo0 = (uint32_t)__ballot(ovl0);
        uint32_t todo1 = (uint32_t)__ballot(ovl1);
        uint32_t t01 = todo0 | todo1;
        if (t01) {
            #pragma unroll
            for (int j = 0; j < NSLOT; ++j) {
                if ((t01 >> j) & 1u) {          // wave-uniform -> scalar branch
                    if ((vm >> j) & 1u) {
                        bool dead = false;
                        if ((todo0 >> j) & 1u) dead = kill_test(sp0.x, sp0.y, sp0.z, sp0.w, s0a, j);
                        if (!dead && ((todo1 >> j) & 1u))
                            dead = kill_test(sp1.x, sp1.y, sp1.z, sp1.w, s1a, j);
                        if (dead) {
                            vm &= ~(1u << j);
                            int r = (int)((rrp[j >> 1] >> ((j & 1) * 16)) & 0xFFFFu);
                            if (r != s0 && r != s1)
                                atomicAnd(&mask[r >> 5], ~(1u << (r & 31)));
                        }
                    }
                }
            }
        }
        scanb = ((s1 >= 0) ? s1 : s0) + 1;
        it += (s1 >= 0) ? 2 : 1;
        __syncthreads();
    }
}

extern "C" void kernel_launch(void* const* d_in, const int* in_sizes, int n_in,
                              void* d_out, int out_size, void* d_ws, size_t ws_size,
                              hipStream_t stream) {
    const float* scores  = (const float*)d_in[0];
    const float* deltas  = (const float*)d_in[1];
    const float* im_info = (const float*)d_in[2];
    const float* anchors = (const float*)d_in[3];
    float* out = (float*)d_out;

    uint8_t* w = (uint8_t*)d_ws;
    uint32_t* hist      = (uint32_t*)(w);                    // 16384 B
    uint64_t* prefix    = (uint64_t*)(w + 16384);            // 128 B
    uint32_t* kth       = (uint32_t*)(w + 16512);            // 64 B
    uint32_t* cnt       = (uint32_t*)(w + 16576);            // 64 B
    uint64_t* selk      = (uint64_t*)(w + 16640);            // 1,536,000 B
    uint32_t* aidx      = (uint32_t*)(w + 1552640);          // 768,000 B
    float*    props     = (float*)(w + 2320640);             // 3,072,000 B
    uint32_t* spat2rank = (uint32_t*)(w + 5392640);          // 768,000 B (end 6,160,640)

    hipLaunchKernelGGL(k_init, dim3(1), dim3(1024), 0, stream, hist, prefix, kth, cnt);
    for (int p = 0; p < 8; ++p) {
        hipLaunchKernelGGL(k_hist, dim3(128, NBATCH), dim3(256), 0, stream, scores, hist, prefix, p);
        hipLaunchKernelGGL(k_pick, dim3(NBATCH), dim3(256), 0, stream, hist, prefix, kth, p);
    }
    hipLaunchKernelGGL(k_compact, dim3(128, NBATCH), dim3(256), 0, stream, scores, prefix, cnt, selk);
    hipLaunchKernelGGL(k_rank, dim3(12, NBATCH), dim3(256), 0, stream, selk, aidx);
    hipLaunchKernelGGL(k_spatsort, dim3(NBATCH), dim3(1024), 0, stream, aidx, spat2rank);
    hipLaunchKernelGGL(k_gather, dim3(47, NBATCH), dim3(256), 0, stream,
                       (const float4*)anchors, (const float4*)deltas, im_info, aidx,
                       (float4*)props);
    hipLaunchKernelGGL(k_nms, dim3(NBATCH), dim3(512), 0, stream,
                       (const float4*)props, spat2rank, out);
}